// Round 1
// baseline (726.025 us; speedup 1.0000x reference)
//
#include <hip/hip_runtime.h>
#include <cstdint>

typedef __attribute__((ext_vector_type(8))) short short8;
typedef __attribute__((ext_vector_type(4))) float f32x4;

#define XB_TILE_BYTES 41472            /* 324 pos * 64 ci * 2B */
#define XB_TILE_U4    2592             /* 16B chunks per tile */
#define N_TILES       2048             /* 8 * 16 * 16 */
#define XB_BYTES      ((size_t)XB_TILE_BYTES * N_TILES)   /* 84,934,656 */
#define WB_OFFSET     (XB_BYTES + 512) /* 256-aligned since XB_BYTES is */

__device__ inline unsigned short f2bf(float f) {
  uint32_t x = __builtin_bit_cast(uint32_t, f);
  uint32_t r = x + 0x7FFFu + ((x >> 16) & 1u);   // RNE
  return (unsigned short)(r >> 16);
}

// ---------------- Pre-pass W: kernels (9,64,64,3,3) fp32 -> bf16 in MFMA
// A-fragment order: Wb[k][uv][kk][mt][lane][j], j = 8 consecutive ci.
// A layout (16x16x32): A[m = lane&15][k = (lane>>4)*8 + j]
__global__ void prep_w(const float* __restrict__ K, unsigned short* __restrict__ Wb) {
  int g = blockIdx.x * 256 + threadIdx.x;      // [0, 41472)
  int l    = g & 63;
  int mt   = (g >> 6) & 3;
  int kk   = (g >> 8) & 1;
  int rest = g >> 9;                            // [0, 81)
  int uv   = rest % 9;
  int kap  = rest / 9;
  int dy = uv / 3, dx = uv % 3;
  int co  = mt * 16 + (l & 15);
  int ci0 = kk * 32 + (l >> 4) * 8;
  unsigned short v[8];
#pragma unroll
  for (int j = 0; j < 8; ++j) {
    int ci = ci0 + j;
    v[j] = f2bf(K[(((kap * 64 + co) * 64 + ci) * 3 + dy) * 3 + dx]);
  }
  uint4 pk;
  pk.x = v[0] | ((uint32_t)v[1] << 16);
  pk.y = v[2] | ((uint32_t)v[3] << 16);
  pk.z = v[4] | ((uint32_t)v[5] << 16);
  pk.w = v[6] | ((uint32_t)v[7] << 16);
  ((uint4*)Wb)[g] = pk;
}

// ---------------- Pre-pass X: inp (8,64,256,256) fp32 ->
// Xb[tile = (b*16+ty)*16+tx][py 0..17][px 0..17][ci 0..63] bf16,
// halo (py/px == 0 or 17) pre-zeroed (per-tile conv zero padding).
__global__ void prep_x(const float* __restrict__ inp, unsigned short* __restrict__ Xb) {
  __shared__ __align__(16) unsigned short xl[64][256];  // [ci][pos] bf16
  int t   = threadIdx.x;
  int blk = blockIdx.x;
  int b = blk >> 8, ty = (blk >> 4) & 15, tx = blk & 15;
  const float* base = inp + (size_t)b * 64 * 65536 + (ty * 16) * 256 + tx * 16;
  // phase 1: coalesced float4 reads -> LDS [ci][pos]
#pragma unroll
  for (int i = 0; i < 16; ++i) {
    int f = i * 256 + t;                // 4096 float4 chunks
    int ci = f >> 6;
    int r = f & 63;
    int iy = r >> 2, ixq = r & 3;
    const float4 v = *(const float4*)(base + (size_t)ci * 65536 + iy * 256 + ixq * 4);
    uint2 pk;
    pk.x = f2bf(v.x) | ((uint32_t)f2bf(v.y) << 16);
    pk.y = f2bf(v.z) | ((uint32_t)f2bf(v.w) << 16);
    *(uint2*)&xl[ci][iy * 16 + ixq * 4] = pk;
  }
  __syncthreads();
  // phase 2: gather 8 ci per 16B chunk, write [pos18][ci] with zero halo
  unsigned short* tileo = Xb + (size_t)blk * (XB_TILE_BYTES / 2);
  for (int i = 0; i < 11; ++i) {
    int c = i * 256 + t;
    if (c >= XB_TILE_U4) break;
    int pos = c >> 3, cib = c & 7;
    int py = pos / 18, px = pos - py * 18;
    uint4 pk = make_uint4(0u, 0u, 0u, 0u);
    if (py >= 1 && py <= 16 && px >= 1 && px <= 16) {
      int p = (py - 1) * 16 + (px - 1);
      unsigned short v[8];
#pragma unroll
      for (int j = 0; j < 8; ++j) v[j] = xl[cib * 8 + j][p];
      pk.x = v[0] | ((uint32_t)v[1] << 16);
      pk.y = v[2] | ((uint32_t)v[3] << 16);
      pk.z = v[4] | ((uint32_t)v[5] << 16);
      pk.w = v[6] | ((uint32_t)v[7] << 16);
    }
    *(uint4*)(tileo + c * 8) = pk;
  }
}

// ---------------- Main: one block per output tile (b,ty,tx).
// Output O[64 co][256 pos] = sum over 9 neighbor tiles x 9 taps x 64 ci,
// via mfma_f32_16x16x32_bf16. 4 waves x (4 mtiles x 4 ntiles), ntile == iy.
__global__ __launch_bounds__(256) void cocov_main(const unsigned short* __restrict__ Xb,
                                                  const unsigned short* __restrict__ Wb,
                                                  float* __restrict__ out) {
  __shared__ __align__(16) unsigned short xl[20736 + 64];  // [pos18][ci] bf16
  int t = threadIdx.x;
  int lane = t & 63, w = t >> 6;
  int n = lane & 15, quad = lane >> 4;
  int blk = blockIdx.x;
  int b = blk >> 8, ty = (blk >> 4) & 15, tx = blk & 15;

  f32x4 acc[4][4];
  const f32x4 zero = {0.0f, 0.0f, 0.0f, 0.0f};
#pragma unroll
  for (int i = 0; i < 4; ++i)
#pragma unroll
    for (int j = 0; j < 4; ++j) acc[i][j] = zero;

  for (int dr = -1; dr <= 1; ++dr) {
    for (int dc = -1; dc <= 1; ++dc) {
      int sy = ty + dr, sx = tx + dc;
      if (sy < 0 || sy > 15 || sx < 0 || sx > 15) continue;  // block-uniform
      int kap = (dr + 1) * 3 + (dc + 1);
      const uint4* tile =
          (const uint4*)(Xb + (size_t)((b * 16 + sy) * 16 + sx) * (XB_TILE_BYTES / 2));
      __syncthreads();                       // previous compute done
      for (int c = t; c < XB_TILE_U4; c += 256) ((uint4*)xl)[c] = tile[c];
      __syncthreads();
      const uint4* wbase = (const uint4*)Wb + (size_t)kap * 9 * 2 * 4 * 64 + lane;
#pragma unroll
      for (int dy = 0; dy < 3; ++dy) {
#pragma unroll
        for (int dx = 0; dx < 3; ++dx) {
          int uv = dy * 3 + dx;
#pragma unroll
          for (int kk = 0; kk < 2; ++kk) {
            const uint4* wp = wbase + (size_t)((uv * 2 + kk) * 4) * 64;
            short8 a[4];
#pragma unroll
            for (int mt = 0; mt < 4; ++mt)
              a[mt] = __builtin_bit_cast(short8, wp[mt * 64]);
            short8 bf[4];
#pragma unroll
            for (int ntl = 0; ntl < 4; ++ntl) {
              int pos = (w * 4 + ntl + dy) * 18 + (n + dx);
              bf[ntl] = *(const short8*)&xl[pos * 64 + kk * 32 + quad * 8];
            }
#pragma unroll
            for (int mt = 0; mt < 4; ++mt)
#pragma unroll
              for (int ntl = 0; ntl < 4; ++ntl)
                acc[mt][ntl] = __builtin_amdgcn_mfma_f32_16x16x32_bf16(
                    a[mt], bf[ntl], acc[mt][ntl], 0, 0, 0);
          }
        }
      }
    }
  }
  // epilogue: D layout row(co) = quad*4+reg, col(ix) = lane&15; iy = w*4+ntl
#pragma unroll
  for (int mt = 0; mt < 4; ++mt)
#pragma unroll
    for (int ntl = 0; ntl < 4; ++ntl) {
      int iy = w * 4 + ntl;
#pragma unroll
      for (int reg = 0; reg < 4; ++reg) {
        int co = mt * 16 + quad * 4 + reg;
        out[(((size_t)b * 64 + co) * 256 + ty * 16 + iy) * 256 + tx * 16 + n] =
            acc[mt][ntl][reg];
      }
    }
}

extern "C" void kernel_launch(void* const* d_in, const int* in_sizes, int n_in,
                              void* d_out, int out_size, void* d_ws, size_t ws_size,
                              hipStream_t stream) {
  const float* inp = (const float*)d_in[0];
  const float* ker = (const float*)d_in[1];
  unsigned short* Xb = (unsigned short*)d_ws;
  unsigned short* Wb = (unsigned short*)((char*)d_ws + WB_OFFSET);
  prep_w<<<162, 256, 0, stream>>>(ker, Wb);
  prep_x<<<2048, 256, 0, stream>>>(inp, Xb);
  cocov_main<<<2048, 256, 0, stream>>>(Xb, Wb, (float*)d_out);
}